// Round 7
// baseline (579.947 us; speedup 1.0000x reference)
//
#include <hip/hip_runtime.h>

// Problem constants (fixed by the reference)
constexpr int NN = 50000;   // nodes
constexpr int NE = 800000;  // edges
constexpr float EPS = 1e-5f;

constexpr int SCAN_BS  = 256;
constexpr int SCAN_NB  = (NN + SCAN_BS - 1) / SCAN_BS;   // 196
constexpr int HIST_NB  = (NE + 255) / 256;               // 3125
constexpr int WCONV_NB = (57344 + 255) / 256;            // 224

typedef short bf16x8 __attribute__((ext_vector_type(8)));
typedef float f32x4  __attribute__((ext_vector_type(4)));

// float -> bf16 bits (RNE, finite values)
__device__ __forceinline__ ushort f2bf(float x) {
    union { float f; unsigned u; } a; a.f = x;
    unsigned u = a.u;
    unsigned r = (u + 0x7FFFu + ((u >> 16) & 1u)) >> 16;
    return (ushort)r;
}
__device__ __forceinline__ float bflo(unsigned p) {
    union { unsigned u; float f; } a; a.u = p << 16; return a.f;
}
__device__ __forceinline__ float bfhi(unsigned p) {
    union { unsigned u; float f; } a; a.u = p & 0xFFFF0000u; return a.f;
}
__device__ __forceinline__ float bf1(ushort p) {
    union { unsigned u; float f; } a; a.u = ((unsigned)p) << 16; return a.f;
}

// ---------------------------------------------------------------------------
// hist + wconv fused (independent work, blockIdx split)
// ---------------------------------------------------------------------------
__global__ void histwconv_kernel(const int* __restrict__ dst, int* __restrict__ counts,
                                 const float* __restrict__ W1, const float* __restrict__ W2,
                                 const float* __restrict__ W3, const float* __restrict__ W4,
                                 ushort* __restrict__ Wt) {
    if (blockIdx.x < HIST_NB) {
        int e = blockIdx.x * 256 + threadIdx.x;
        if (e < NE) atomicAdd(&counts[dst[e]], 1);
    } else {
        int id = (blockIdx.x - HIST_NB) * 256 + threadIdx.x;
        if (id < 49152) {
            int l = id / 16384, r = id % 16384;
            int n = r >> 7, k = r & 127;
            const float* W = (l == 0) ? W1 : (l == 1) ? W2 : W3;
            Wt[l * 16384 + n * 128 + k] = f2bf(W[k * 128 + n]);
        } else if (id < 57344) {
            int r = id - 49152;
            int n = r >> 7, k = r & 127;
            Wt[49152 + n * 128 + k] = f2bf(W4[k * 64 + n]);
        }
    }
}

__global__ __launch_bounds__(SCAN_BS) void blocksum_kernel(const int* __restrict__ counts,
                                                           int* __restrict__ bsum) {
    __shared__ int s[SCAN_BS];
    int t = threadIdx.x;
    int i = blockIdx.x * SCAN_BS + t;
    s[t] = (i < NN) ? counts[i] : 0;
    __syncthreads();
    for (int off = SCAN_BS / 2; off > 0; off >>= 1) {
        if (t < off) s[t] += s[t + off];
        __syncthreads();
    }
    if (t == 0) bsum[blockIdx.x] = s[0];
}

__global__ __launch_bounds__(SCAN_BS) void scanbsum_kernel(int* __restrict__ bsum) {
    __shared__ int s[SCAN_BS];
    int t = threadIdx.x;
    int v = (t < SCAN_NB) ? bsum[t] : 0;
    s[t] = v;
    __syncthreads();
    for (int off = 1; off < SCAN_BS; off <<= 1) {
        int x = (t >= off) ? s[t - off] : 0;
        __syncthreads();
        s[t] += x;
        __syncthreads();
    }
    if (t < SCAN_NB) bsum[t] = s[t] - v;   // exclusive
}

// scanfinal + dinv fused
__global__ __launch_bounds__(SCAN_BS) void scanfinal_kernel(const int* __restrict__ counts,
                                                            const int* __restrict__ bsum,
                                                            int* __restrict__ rowstart,
                                                            float* __restrict__ dinv) {
    __shared__ int s[SCAN_BS];
    int t = threadIdx.x;
    int i = blockIdx.x * SCAN_BS + t;
    int c = (i < NN) ? counts[i] : 0;
    s[t] = c;
    __syncthreads();
    for (int off = 1; off < SCAN_BS; off <<= 1) {
        int x = (t >= off) ? s[t - off] : 0;
        __syncthreads();
        s[t] += x;
        __syncthreads();
    }
    if (i < NN) {
        rowstart[i] = s[t] - c + bsum[blockIdx.x];
        dinv[i] = rsqrtf((float)c + 1.0f);
    }
}

__global__ void fill_kernel(const int* __restrict__ src, const int* __restrict__ dst,
                            const int* __restrict__ rowstart, int* __restrict__ cursor,
                            ushort* __restrict__ csr) {
    int e = blockIdx.x * 256 + threadIdx.x;
    if (e >= NE) return;
    int d = dst[e];
    int pos = rowstart[d] + atomicAdd(&cursor[d], 1);
    csr[pos] = (ushort)src[e];
}

// ---------------------------------------------------------------------------
// MFMA GEMM, W-in-registers: U(bf16) = bf16( relu?(X*sc+sh) @ W ) * dinv[row]
// Block: 256 thr (4 waves), 128 rows. Each wave: 32 rows (2 A-frags),
// full F cols. W held in VGPRs (NT*4 bf16x8 per lane), A staged in LDS.
// Inner loop: 2 ds_read_b128 per 16 MFMA -> MFMA-bound.
// ---------------------------------------------------------------------------
template<int F, bool BN>
__global__ __launch_bounds__(256, 2) void gemm_bf16_kernel(
    const void* __restrict__ Xv, const ushort* __restrict__ Wt,
    const float* __restrict__ dinv, const float* __restrict__ sc,
    const float* __restrict__ sh, ushort* __restrict__ U)
{
    constexpr int NT  = F / 16;   // col tiles
    constexpr int LDK = 136;
    __shared__ __align__(16) ushort Xs[128 * LDK];

    const int tid  = threadIdx.x;
    const int wave = tid >> 6;
    const int lane = tid & 63;
    const int m    = lane & 15;
    const int q    = lane >> 4;
    const int row0 = blockIdx.x * 128;

    // W fragments -> registers (same for every block; L1/L2-hot)
    bf16x8 w[NT][4];
#pragma unroll
    for (int nt = 0; nt < NT; nt++)
#pragma unroll
        for (int ks = 0; ks < 4; ks++)
            w[nt][ks] = *(const bf16x8*)&Wt[(nt * 16 + m) * 128 + ks * 32 + q * 8];

    // stage X (+BN+ReLU) -> bf16 LDS: 128 rows x 128 cols, 16 iters/thread
#pragma unroll
    for (int it = 0; it < 16; it++) {
        int idx = it * 256 + tid;
        int r   = idx >> 5;
        int c4  = (idx & 31) * 4;
        int row = row0 + r;
        float4 v = make_float4(0.f, 0.f, 0.f, 0.f);
        if constexpr (BN) {
            if (row < NN) {
                uint2 p = *(const uint2*)&((const ushort*)Xv)[(size_t)row * 128 + c4];
                v.x = bflo(p.x); v.y = bfhi(p.x);
                v.z = bflo(p.y); v.w = bfhi(p.y);
            }
            float4 s = *(const float4*)&sc[c4];
            float4 h = *(const float4*)&sh[c4];
            v.x = fmaxf(0.f, v.x * s.x + h.x);
            v.y = fmaxf(0.f, v.y * s.y + h.y);
            v.z = fmaxf(0.f, v.z * s.z + h.z);
            v.w = fmaxf(0.f, v.w * s.w + h.w);
        } else {
            if (row < NN) v = *(const float4*)&((const float*)Xv)[(size_t)row * 128 + c4];
        }
        ushort4 o;
        o.x = f2bf(v.x); o.y = f2bf(v.y); o.z = f2bf(v.z); o.w = f2bf(v.w);
        *(ushort4*)&Xs[r * LDK + c4] = o;
    }
    __syncthreads();

    f32x4 acc[2][NT];
#pragma unroll
    for (int t = 0; t < 2; t++)
#pragma unroll
        for (int nt = 0; nt < NT; nt++) acc[t][nt] = (f32x4){0.f, 0.f, 0.f, 0.f};

#pragma unroll
    for (int ks = 0; ks < 4; ks++) {
        bf16x8 a0 = *(const bf16x8*)&Xs[(wave * 32 + m)      * LDK + ks * 32 + q * 8];
        bf16x8 a1 = *(const bf16x8*)&Xs[(wave * 32 + 16 + m) * LDK + ks * 32 + q * 8];
#pragma unroll
        for (int nt = 0; nt < NT; nt++) {
            acc[0][nt] = __builtin_amdgcn_mfma_f32_16x16x32_bf16(a0, w[nt][ks], acc[0][nt], 0, 0, 0);
            acc[1][nt] = __builtin_amdgcn_mfma_f32_16x16x32_bf16(a1, w[nt][ks], acc[1][nt], 0, 0, 0);
        }
    }

#pragma unroll
    for (int t = 0; t < 2; t++) {
#pragma unroll
        for (int r = 0; r < 4; r++) {
            int row = row0 + wave * 32 + t * 16 + q * 4 + r;
            if (row < NN) {
                float di = dinv[row];
#pragma unroll
                for (int nt = 0; nt < NT; nt++) {
                    U[(size_t)row * F + nt * 16 + m] = f2bf(acc[t][nt][r] * di);
                }
            }
        }
    }
}

// ---------------------------------------------------------------------------
// Gather (atomic-free): ONE wave per node, fire-and-exit (proven shape).
// ---------------------------------------------------------------------------
__global__ __launch_bounds__(256) void gather128_kernel(
    const ushort* __restrict__ csr, const int* __restrict__ rowst,
    const int* __restrict__ counts, const ushort* __restrict__ U,
    const float* __restrict__ dinv, const float* __restrict__ b,
    ushort* __restrict__ Yb)
{
    int n    = (blockIdx.x * 256 + threadIdx.x) >> 6;
    int lane = threadIdx.x & 63;
    if (n >= NN) return;
    const int coff = lane * 2;
    int base = rowst[n];
    int deg  = counts[n];
    float ax = 0.f, ay = 0.f;
    int j = 0;
    for (; j + 4 <= deg; j += 4) {
        int s0 = csr[base + j + 0];
        int s1 = csr[base + j + 1];
        int s2 = csr[base + j + 2];
        int s3 = csr[base + j + 3];
        unsigned u0 = *(const unsigned*)&U[(size_t)s0 * 128 + coff];
        unsigned u1 = *(const unsigned*)&U[(size_t)s1 * 128 + coff];
        unsigned u2 = *(const unsigned*)&U[(size_t)s2 * 128 + coff];
        unsigned u3 = *(const unsigned*)&U[(size_t)s3 * 128 + coff];
        ax += bflo(u0) + bflo(u1) + bflo(u2) + bflo(u3);
        ay += bfhi(u0) + bfhi(u1) + bfhi(u2) + bfhi(u3);
    }
    for (; j < deg; j++) {
        int s = csr[base + j];
        unsigned u = *(const unsigned*)&U[(size_t)s * 128 + coff];
        ax += bflo(u); ay += bfhi(u);
    }
    unsigned us = *(const unsigned*)&U[(size_t)n * 128 + coff];
    float di = dinv[n];
    float ox = di * (ax + bflo(us)) + b[coff];
    float oy = di * (ay + bfhi(us)) + b[coff + 1];
    unsigned pk = (unsigned)f2bf(ox) | ((unsigned)f2bf(oy) << 16);
    *(unsigned*)&Yb[(size_t)n * 128 + coff] = pk;
}

__global__ __launch_bounds__(256) void gather64_kernel(
    const ushort* __restrict__ csr, const int* __restrict__ rowst,
    const int* __restrict__ counts, const ushort* __restrict__ U,
    const float* __restrict__ dinv, const float* __restrict__ b,
    float* __restrict__ Y)
{
    int n    = (blockIdx.x * 256 + threadIdx.x) >> 6;
    int lane = threadIdx.x & 63;
    if (n >= NN) return;
    int base = rowst[n];
    int deg  = counts[n];
    float a = 0.f;
    int j = 0;
    for (; j + 4 <= deg; j += 4) {
        int s0 = csr[base + j + 0];
        int s1 = csr[base + j + 1];
        int s2 = csr[base + j + 2];
        int s3 = csr[base + j + 3];
        a += bf1(U[(size_t)s0 * 64 + lane]) + bf1(U[(size_t)s1 * 64 + lane])
           + bf1(U[(size_t)s2 * 64 + lane]) + bf1(U[(size_t)s3 * 64 + lane]);
    }
    for (; j < deg; j++) {
        int s = csr[base + j];
        a += bf1(U[(size_t)s * 64 + lane]);
    }
    float self = bf1(U[(size_t)n * 64 + lane]);
    Y[(size_t)n * 64 + lane] = dinv[n] * (a + self) + b[lane];
}

// ---------------------------------------------------------------------------
// BN stats + prep fused (last-block pattern; device-scope atomics for all
// cross-block traffic per XCD non-coherence rules). Re-zeros sums/done.
// ---------------------------------------------------------------------------
__global__ __launch_bounds__(128) void stats_prep_kernel(
    const ushort* __restrict__ Yb, float* __restrict__ sums, float* __restrict__ sumsq,
    int* __restrict__ done, const float* __restrict__ g, const float* __restrict__ be,
    float* __restrict__ sc, float* __restrict__ sh)
{
    int col = threadIdx.x;
    float ls = 0.f, lq = 0.f;
    for (int row = blockIdx.x; row < NN; row += gridDim.x) {
        float y = bf1(Yb[(size_t)row * 128 + col]);
        ls += y;
        lq += y * y;
    }
    atomicAdd(&sums[col], ls);
    atomicAdd(&sumsq[col], lq);
    __threadfence();
    __shared__ int ticket;
    if (threadIdx.x == 0) ticket = atomicAdd(done, 1);
    __syncthreads();
    if (ticket == (int)gridDim.x - 1) {
        float s  = atomicAdd(&sums[col], 0.f);    // coherent read
        float qq = atomicAdd(&sumsq[col], 0.f);
        float mu  = s * (1.0f / NN);
        float var = qq * (1.0f / NN) - mu * mu;
        float scv = rsqrtf(var + EPS) * g[col];
        sc[col] = scv;                // consumed after kernel boundary: plain ok
        sh[col] = be[col] - mu * scv;
        atomicExch(&sums[col], 0.f);  // coherent reset for next layer
        atomicExch(&sumsq[col], 0.f);
        if (col == 0) atomicExch(done, 0);
    }
}

// ---------------------------------------------------------------------------
extern "C" void kernel_launch(void* const* d_in, const int* in_sizes, int n_in,
                              void* d_out, int out_size, void* d_ws, size_t ws_size,
                              hipStream_t stream)
{
    const float* x   = (const float*)d_in[0];
    const int*   ei  = (const int*)d_in[1];
    const int*   src = ei;
    const int*   dst = ei + NE;
    const float* W1 = (const float*)d_in[2];  const float* b1 = (const float*)d_in[3];
    const float* W2 = (const float*)d_in[4];  const float* b2 = (const float*)d_in[5];
    const float* W3 = (const float*)d_in[6];  const float* b3 = (const float*)d_in[7];
    const float* W4 = (const float*)d_in[8];  const float* b4 = (const float*)d_in[9];
    const float* g1 = (const float*)d_in[10]; const float* be1 = (const float*)d_in[11];
    const float* g2 = (const float*)d_in[12]; const float* be2 = (const float*)d_in[13];
    const float* g3 = (const float*)d_in[14]; const float* be3 = (const float*)d_in[15];
    float* out = (float*)d_out;

    // workspace layout (~29 MB)
    char* wsb = (char*)d_ws;
    float* dinv   = (float*)wsb;                    // NN f
    int*   counts = (int*)(dinv + NN);              // NN i   (counts+cursor: one memset)
    int*   cursor = counts + NN;                    // NN i
    int*   rowst  = cursor + NN;                    // NN i
    int*   bsum   = rowst + NN;                     // 256 i
    float* sums   = (float*)(bsum + 256);           // 128 f  (sums+sumsq+done: one memset)
    float* sumsq  = sums + 128;                     // 128 f
    int*   done   = (int*)(sumsq + 128);            // 4 i
    float* sc     = (float*)(done + 4);             // 128 f
    float* sh     = sc + 128;                       // 128 f
    ushort* Wt    = (ushort*)(sh + 128);            // 57344 us (16B-aligned)
    ushort* csr   = Wt + 57344;                     // NE us (1.6 MB)
    ushort* Yb    = csr + NE;                       // NN*128 us (bf16 Y)
    ushort* U     = Yb + (size_t)NN * 128;          // NN*128 us (bf16 U)

    const ushort* Wt1 = Wt;
    const ushort* Wt2 = Wt + 16384;
    const ushort* Wt3 = Wt + 32768;
    const ushort* Wt4 = Wt + 49152;

    const int gemmGrid = (NN + 127) / 128;        // 391
    const int gathGrid = (NN * 64 + 255) / 256;   // one wave per node, fire-and-exit

    // ---- prep: CSR + dinv + weights + zeroed stats
    hipMemsetAsync(counts, 0, 2 * NN * sizeof(int), stream);          // counts+cursor
    hipMemsetAsync(sums, 0, (256 * sizeof(float) + 4 * sizeof(int)), stream);
    histwconv_kernel<<<HIST_NB + WCONV_NB, 256, 0, stream>>>(dst, counts, W1, W2, W3, W4, Wt);
    blocksum_kernel<<<SCAN_NB, SCAN_BS, 0, stream>>>(counts, bsum);
    scanbsum_kernel<<<1, SCAN_BS, 0, stream>>>(bsum);
    scanfinal_kernel<<<SCAN_NB, SCAN_BS, 0, stream>>>(counts, bsum, rowst, dinv);
    fill_kernel<<<HIST_NB, 256, 0, stream>>>(src, dst, rowst, cursor, csr);

    // ---- Layer 1
    gemm_bf16_kernel<128, false><<<gemmGrid, 256, 0, stream>>>(x, Wt1, dinv, sc, sh, U);
    gather128_kernel<<<gathGrid, 256, 0, stream>>>(csr, rowst, counts, U, dinv, b1, Yb);
    stats_prep_kernel<<<960, 128, 0, stream>>>(Yb, sums, sumsq, done, g1, be1, sc, sh);

    // ---- Layer 2
    gemm_bf16_kernel<128, true><<<gemmGrid, 256, 0, stream>>>(Yb, Wt2, dinv, sc, sh, U);
    gather128_kernel<<<gathGrid, 256, 0, stream>>>(csr, rowst, counts, U, dinv, b2, Yb);
    stats_prep_kernel<<<960, 128, 0, stream>>>(Yb, sums, sumsq, done, g2, be2, sc, sh);

    // ---- Layer 3
    gemm_bf16_kernel<128, true><<<gemmGrid, 256, 0, stream>>>(Yb, Wt3, dinv, sc, sh, U);
    gather128_kernel<<<gathGrid, 256, 0, stream>>>(csr, rowst, counts, U, dinv, b3, Yb);
    stats_prep_kernel<<<960, 128, 0, stream>>>(Yb, sums, sumsq, done, g3, be3, sc, sh);

    // ---- Layer 4 (no BN stats; gather straight to d_out)
    gemm_bf16_kernel<64, true><<<gemmGrid, 256, 0, stream>>>(Yb, Wt4, dinv, sc, sh, U);
    gather64_kernel<<<gathGrid, 256, 0, stream>>>(csr, rowst, counts, U, dinv, b4, out);
}

// Round 8
// 475.989 us; speedup vs baseline: 1.2184x; 1.2184x over previous
//
#include <hip/hip_runtime.h>

// Problem constants (fixed by the reference)
constexpr int NN = 50000;   // nodes
constexpr int NE = 800000;  // edges
constexpr float EPS = 1e-5f;

constexpr int SCAN_BS  = 256;
constexpr int SCAN_NB  = (NN + SCAN_BS - 1) / SCAN_BS;   // 196
constexpr int HIST_NB  = (NE + 255) / 256;               // 3125
constexpr int WCONV_NB = (57344 + 255) / 256;            // 224

typedef short bf16x8 __attribute__((ext_vector_type(8)));
typedef float f32x4  __attribute__((ext_vector_type(4)));

// float -> bf16 bits (RNE, finite values)
__device__ __forceinline__ ushort f2bf(float x) {
    union { float f; unsigned u; } a; a.f = x;
    unsigned u = a.u;
    unsigned r = (u + 0x7FFFu + ((u >> 16) & 1u)) >> 16;
    return (ushort)r;
}
__device__ __forceinline__ float bflo(unsigned p) {
    union { unsigned u; float f; } a; a.u = p << 16; return a.f;
}
__device__ __forceinline__ float bfhi(unsigned p) {
    union { unsigned u; float f; } a; a.u = p & 0xFFFF0000u; return a.f;
}
__device__ __forceinline__ float bf1(ushort p) {
    union { unsigned u; float f; } a; a.u = ((unsigned)p) << 16; return a.f;
}

// ---------------------------------------------------------------------------
// hist + wconv fused (independent work, blockIdx split)
// ---------------------------------------------------------------------------
__global__ void histwconv_kernel(const int* __restrict__ dst, int* __restrict__ counts,
                                 const float* __restrict__ W1, const float* __restrict__ W2,
                                 const float* __restrict__ W3, const float* __restrict__ W4,
                                 ushort* __restrict__ Wt) {
    if (blockIdx.x < HIST_NB) {
        int e = blockIdx.x * 256 + threadIdx.x;
        if (e < NE) atomicAdd(&counts[dst[e]], 1);
    } else {
        int id = (blockIdx.x - HIST_NB) * 256 + threadIdx.x;
        if (id < 49152) {
            int l = id / 16384, r = id % 16384;
            int n = r >> 7, k = r & 127;
            const float* W = (l == 0) ? W1 : (l == 1) ? W2 : W3;
            Wt[l * 16384 + n * 128 + k] = f2bf(W[k * 128 + n]);
        } else if (id < 57344) {
            int r = id - 49152;
            int n = r >> 7, k = r & 127;
            Wt[49152 + n * 128 + k] = f2bf(W4[k * 64 + n]);
        }
    }
}

__global__ __launch_bounds__(SCAN_BS) void blocksum_kernel(const int* __restrict__ counts,
                                                           int* __restrict__ bsum) {
    __shared__ int s[SCAN_BS];
    int t = threadIdx.x;
    int i = blockIdx.x * SCAN_BS + t;
    s[t] = (i < NN) ? counts[i] : 0;
    __syncthreads();
    for (int off = SCAN_BS / 2; off > 0; off >>= 1) {
        if (t < off) s[t] += s[t + off];
        __syncthreads();
    }
    if (t == 0) bsum[blockIdx.x] = s[0];
}

__global__ __launch_bounds__(SCAN_BS) void scanbsum_kernel(int* __restrict__ bsum) {
    __shared__ int s[SCAN_BS];
    int t = threadIdx.x;
    int v = (t < SCAN_NB) ? bsum[t] : 0;
    s[t] = v;
    __syncthreads();
    for (int off = 1; off < SCAN_BS; off <<= 1) {
        int x = (t >= off) ? s[t - off] : 0;
        __syncthreads();
        s[t] += x;
        __syncthreads();
    }
    if (t < SCAN_NB) bsum[t] = s[t] - v;   // exclusive
}

// scanfinal + dinv fused
__global__ __launch_bounds__(SCAN_BS) void scanfinal_kernel(const int* __restrict__ counts,
                                                            const int* __restrict__ bsum,
                                                            int* __restrict__ rowstart,
                                                            float* __restrict__ dinv) {
    __shared__ int s[SCAN_BS];
    int t = threadIdx.x;
    int i = blockIdx.x * SCAN_BS + t;
    int c = (i < NN) ? counts[i] : 0;
    s[t] = c;
    __syncthreads();
    for (int off = 1; off < SCAN_BS; off <<= 1) {
        int x = (t >= off) ? s[t - off] : 0;
        __syncthreads();
        s[t] += x;
        __syncthreads();
    }
    if (i < NN) {
        rowstart[i] = s[t] - c + bsum[blockIdx.x];
        dinv[i] = rsqrtf((float)c + 1.0f);
    }
}

__global__ void fill_kernel(const int* __restrict__ src, const int* __restrict__ dst,
                            const int* __restrict__ rowstart, int* __restrict__ cursor,
                            ushort* __restrict__ csr) {
    int e = blockIdx.x * 256 + threadIdx.x;
    if (e >= NE) return;
    int d = dst[e];
    int pos = rowstart[d] + atomicAdd(&cursor[d], 1);
    csr[pos] = (ushort)src[e];
}

// ---------------------------------------------------------------------------
// MFMA GEMM, W-in-registers: U(bf16) = bf16( relu?(X*sc+sh) @ W ) * dinv[row]
// Block: 256 thr (4 waves), 128 rows. Each wave: 32 rows (2 A-frags),
// full F cols. W held in VGPRs (NT*4 bf16x8 per lane), A staged in LDS.
// ---------------------------------------------------------------------------
template<int F, bool BN>
__global__ __launch_bounds__(256, 2) void gemm_bf16_kernel(
    const void* __restrict__ Xv, const ushort* __restrict__ Wt,
    const float* __restrict__ dinv, const float* __restrict__ sc,
    const float* __restrict__ sh, ushort* __restrict__ U)
{
    constexpr int NT  = F / 16;   // col tiles
    constexpr int LDK = 136;
    __shared__ __align__(16) ushort Xs[128 * LDK];

    const int tid  = threadIdx.x;
    const int wave = tid >> 6;
    const int lane = tid & 63;
    const int m    = lane & 15;
    const int q    = lane >> 4;
    const int row0 = blockIdx.x * 128;

    // W fragments -> registers (same for every block; L1/L2-hot)
    bf16x8 w[NT][4];
#pragma unroll
    for (int nt = 0; nt < NT; nt++)
#pragma unroll
        for (int ks = 0; ks < 4; ks++)
            w[nt][ks] = *(const bf16x8*)&Wt[(nt * 16 + m) * 128 + ks * 32 + q * 8];

    // stage X (+BN+ReLU) -> bf16 LDS: 128 rows x 128 cols, 16 iters/thread
#pragma unroll
    for (int it = 0; it < 16; it++) {
        int idx = it * 256 + tid;
        int r   = idx >> 5;
        int c4  = (idx & 31) * 4;
        int row = row0 + r;
        float4 v = make_float4(0.f, 0.f, 0.f, 0.f);
        if constexpr (BN) {
            if (row < NN) {
                uint2 p = *(const uint2*)&((const ushort*)Xv)[(size_t)row * 128 + c4];
                v.x = bflo(p.x); v.y = bfhi(p.x);
                v.z = bflo(p.y); v.w = bfhi(p.y);
            }
            float4 s = *(const float4*)&sc[c4];
            float4 h = *(const float4*)&sh[c4];
            v.x = fmaxf(0.f, v.x * s.x + h.x);
            v.y = fmaxf(0.f, v.y * s.y + h.y);
            v.z = fmaxf(0.f, v.z * s.z + h.z);
            v.w = fmaxf(0.f, v.w * s.w + h.w);
        } else {
            if (row < NN) v = *(const float4*)&((const float*)Xv)[(size_t)row * 128 + c4];
        }
        ushort4 o;
        o.x = f2bf(v.x); o.y = f2bf(v.y); o.z = f2bf(v.z); o.w = f2bf(v.w);
        *(ushort4*)&Xs[r * LDK + c4] = o;
    }
    __syncthreads();

    f32x4 acc[2][NT];
#pragma unroll
    for (int t = 0; t < 2; t++)
#pragma unroll
        for (int nt = 0; nt < NT; nt++) acc[t][nt] = (f32x4){0.f, 0.f, 0.f, 0.f};

#pragma unroll
    for (int ks = 0; ks < 4; ks++) {
        bf16x8 a0 = *(const bf16x8*)&Xs[(wave * 32 + m)      * LDK + ks * 32 + q * 8];
        bf16x8 a1 = *(const bf16x8*)&Xs[(wave * 32 + 16 + m) * LDK + ks * 32 + q * 8];
#pragma unroll
        for (int nt = 0; nt < NT; nt++) {
            acc[0][nt] = __builtin_amdgcn_mfma_f32_16x16x32_bf16(a0, w[nt][ks], acc[0][nt], 0, 0, 0);
            acc[1][nt] = __builtin_amdgcn_mfma_f32_16x16x32_bf16(a1, w[nt][ks], acc[1][nt], 0, 0, 0);
        }
    }

#pragma unroll
    for (int t = 0; t < 2; t++) {
#pragma unroll
        for (int r = 0; r < 4; r++) {
            int row = row0 + wave * 32 + t * 16 + q * 4 + r;
            if (row < NN) {
                float di = dinv[row];
#pragma unroll
                for (int nt = 0; nt < NT; nt++) {
                    U[(size_t)row * F + nt * 16 + m] = f2bf(acc[t][nt][r] * di);
                }
            }
        }
    }
}

// ---------------------------------------------------------------------------
// Gather (atomic-free): ONE wave per node, fire-and-exit (proven shape).
// ---------------------------------------------------------------------------
__global__ __launch_bounds__(256) void gather128_kernel(
    const ushort* __restrict__ csr, const int* __restrict__ rowst,
    const int* __restrict__ counts, const ushort* __restrict__ U,
    const float* __restrict__ dinv, const float* __restrict__ b,
    ushort* __restrict__ Yb)
{
    int n    = (blockIdx.x * 256 + threadIdx.x) >> 6;
    int lane = threadIdx.x & 63;
    if (n >= NN) return;
    const int coff = lane * 2;
    int base = rowst[n];
    int deg  = counts[n];
    float ax = 0.f, ay = 0.f;
    int j = 0;
    for (; j + 4 <= deg; j += 4) {
        int s0 = csr[base + j + 0];
        int s1 = csr[base + j + 1];
        int s2 = csr[base + j + 2];
        int s3 = csr[base + j + 3];
        unsigned u0 = *(const unsigned*)&U[(size_t)s0 * 128 + coff];
        unsigned u1 = *(const unsigned*)&U[(size_t)s1 * 128 + coff];
        unsigned u2 = *(const unsigned*)&U[(size_t)s2 * 128 + coff];
        unsigned u3 = *(const unsigned*)&U[(size_t)s3 * 128 + coff];
        ax += bflo(u0) + bflo(u1) + bflo(u2) + bflo(u3);
        ay += bfhi(u0) + bfhi(u1) + bfhi(u2) + bfhi(u3);
    }
    for (; j < deg; j++) {
        int s = csr[base + j];
        unsigned u = *(const unsigned*)&U[(size_t)s * 128 + coff];
        ax += bflo(u); ay += bfhi(u);
    }
    unsigned us = *(const unsigned*)&U[(size_t)n * 128 + coff];
    float di = dinv[n];
    float ox = di * (ax + bflo(us)) + b[coff];
    float oy = di * (ay + bfhi(us)) + b[coff + 1];
    unsigned pk = (unsigned)f2bf(ox) | ((unsigned)f2bf(oy) << 16);
    *(unsigned*)&Yb[(size_t)n * 128 + coff] = pk;
}

__global__ __launch_bounds__(256) void gather64_kernel(
    const ushort* __restrict__ csr, const int* __restrict__ rowst,
    const int* __restrict__ counts, const ushort* __restrict__ U,
    const float* __restrict__ dinv, const float* __restrict__ b,
    float* __restrict__ Y)
{
    int n    = (blockIdx.x * 256 + threadIdx.x) >> 6;
    int lane = threadIdx.x & 63;
    if (n >= NN) return;
    int base = rowst[n];
    int deg  = counts[n];
    float a = 0.f;
    int j = 0;
    for (; j + 4 <= deg; j += 4) {
        int s0 = csr[base + j + 0];
        int s1 = csr[base + j + 1];
        int s2 = csr[base + j + 2];
        int s3 = csr[base + j + 3];
        a += bf1(U[(size_t)s0 * 64 + lane]) + bf1(U[(size_t)s1 * 64 + lane])
           + bf1(U[(size_t)s2 * 64 + lane]) + bf1(U[(size_t)s3 * 64 + lane]);
    }
    for (; j < deg; j++) {
        int s = csr[base + j];
        a += bf1(U[(size_t)s * 64 + lane]);
    }
    float self = bf1(U[(size_t)n * 64 + lane]);
    Y[(size_t)n * 64 + lane] = dinv[n] * (a + self) + b[lane];
}

// ---------------------------------------------------------------------------
// BN stats (read-only, no fence): one wave reads a full 256 B row per iter
// (lane l -> cols 2l,2l+1 as dword). 512 blocks x 4 waves. Block-level LDS
// reduce, then 256 global atomics per block.
// ---------------------------------------------------------------------------
__global__ __launch_bounds__(256) void stats_kernel(const ushort* __restrict__ Yb,
                                                    float* __restrict__ sums,
                                                    float* __restrict__ sumsq)
{
    __shared__ float ssum[128], ssq[128];
    if (threadIdx.x < 128) { ssum[threadIdx.x] = 0.f; ssq[threadIdx.x] = 0.f; }
    __syncthreads();

    const int lane   = threadIdx.x & 63;
    const int gwave  = (blockIdx.x * 256 + threadIdx.x) >> 6;
    const int nWaves = gridDim.x * 4;
    const int coff   = lane * 2;

    float s0 = 0.f, s1 = 0.f, q0 = 0.f, q1 = 0.f;
    for (int row = gwave; row < NN; row += nWaves) {
        unsigned p = *(const unsigned*)&Yb[(size_t)row * 128 + coff];
        float yx = bflo(p), yy = bfhi(p);
        s0 += yx; q0 += yx * yx;
        s1 += yy; q1 += yy * yy;
    }
    atomicAdd(&ssum[coff], s0);     atomicAdd(&ssum[coff + 1], s1);
    atomicAdd(&ssq[coff], q0);      atomicAdd(&ssq[coff + 1], q1);
    __syncthreads();
    if (threadIdx.x < 128) {
        atomicAdd(&sums[threadIdx.x],  ssum[threadIdx.x]);
        atomicAdd(&sumsq[threadIdx.x], ssq[threadIdx.x]);
    }
}

// BN prep: sums/sumsq -> sc/sh, then re-zero sums/sumsq for next layer.
__global__ void bn_prep_kernel(float* __restrict__ sums, float* __restrict__ sumsq,
                               const float* __restrict__ g, const float* __restrict__ be,
                               float* __restrict__ sc, float* __restrict__ sh)
{
    int c = threadIdx.x;
    float mu  = sums[c] * (1.0f / NN);
    float var = sumsq[c] * (1.0f / NN) - mu * mu;
    float s   = rsqrtf(var + EPS) * g[c];
    sc[c] = s;
    sh[c] = be[c] - mu * s;
    sums[c]  = 0.f;
    sumsq[c] = 0.f;
}

// ---------------------------------------------------------------------------
extern "C" void kernel_launch(void* const* d_in, const int* in_sizes, int n_in,
                              void* d_out, int out_size, void* d_ws, size_t ws_size,
                              hipStream_t stream)
{
    const float* x   = (const float*)d_in[0];
    const int*   ei  = (const int*)d_in[1];
    const int*   src = ei;
    const int*   dst = ei + NE;
    const float* W1 = (const float*)d_in[2];  const float* b1 = (const float*)d_in[3];
    const float* W2 = (const float*)d_in[4];  const float* b2 = (const float*)d_in[5];
    const float* W3 = (const float*)d_in[6];  const float* b3 = (const float*)d_in[7];
    const float* W4 = (const float*)d_in[8];  const float* b4 = (const float*)d_in[9];
    const float* g1 = (const float*)d_in[10]; const float* be1 = (const float*)d_in[11];
    const float* g2 = (const float*)d_in[12]; const float* be2 = (const float*)d_in[13];
    const float* g3 = (const float*)d_in[14]; const float* be3 = (const float*)d_in[15];
    float* out = (float*)d_out;

    // workspace layout (~29 MB)
    char* wsb = (char*)d_ws;
    float* dinv   = (float*)wsb;                    // NN f
    int*   counts = (int*)(dinv + NN);              // NN i   (counts+cursor: one memset)
    int*   cursor = counts + NN;                    // NN i
    int*   rowst  = cursor + NN;                    // NN i
    int*   bsum   = rowst + NN;                     // 256 i
    float* sums   = (float*)(bsum + 256);           // 128 f  (sums+sumsq: one memset)
    float* sumsq  = sums + 128;                     // 128 f
    float* sc     = sumsq + 128;                    // 128 f
    float* sh     = sc + 128;                       // 128 f
    ushort* Wt    = (ushort*)(sh + 128);            // 57344 us (16B-aligned)
    ushort* csr   = Wt + 57344;                     // NE us (1.6 MB)
    ushort* Yb    = csr + NE;                       // NN*128 us (bf16 Y)
    ushort* U     = Yb + (size_t)NN * 128;          // NN*128 us (bf16 U)

    const ushort* Wt1 = Wt;
    const ushort* Wt2 = Wt + 16384;
    const ushort* Wt3 = Wt + 32768;
    const ushort* Wt4 = Wt + 49152;

    const int gemmGrid = (NN + 127) / 128;        // 391
    const int gathGrid = (NN * 64 + 255) / 256;   // one wave per node, fire-and-exit

    // ---- prep: CSR + dinv + weights + zeroed stats
    hipMemsetAsync(counts, 0, 2 * NN * sizeof(int), stream);          // counts+cursor
    hipMemsetAsync(sums, 0, 256 * sizeof(float), stream);             // sums+sumsq
    histwconv_kernel<<<HIST_NB + WCONV_NB, 256, 0, stream>>>(dst, counts, W1, W2, W3, W4, Wt);
    blocksum_kernel<<<SCAN_NB, SCAN_BS, 0, stream>>>(counts, bsum);
    scanbsum_kernel<<<1, SCAN_BS, 0, stream>>>(bsum);
    scanfinal_kernel<<<SCAN_NB, SCAN_BS, 0, stream>>>(counts, bsum, rowst, dinv);
    fill_kernel<<<HIST_NB, 256, 0, stream>>>(src, dst, rowst, cursor, csr);

    // ---- Layer 1
    gemm_bf16_kernel<128, false><<<gemmGrid, 256, 0, stream>>>(x, Wt1, dinv, sc, sh, U);
    gather128_kernel<<<gathGrid, 256, 0, stream>>>(csr, rowst, counts, U, dinv, b1, Yb);
    stats_kernel<<<512, 256, 0, stream>>>(Yb, sums, sumsq);
    bn_prep_kernel<<<1, 128, 0, stream>>>(sums, sumsq, g1, be1, sc, sh);

    // ---- Layer 2
    gemm_bf16_kernel<128, true><<<gemmGrid, 256, 0, stream>>>(Yb, Wt2, dinv, sc, sh, U);
    gather128_kernel<<<gathGrid, 256, 0, stream>>>(csr, rowst, counts, U, dinv, b2, Yb);
    stats_kernel<<<512, 256, 0, stream>>>(Yb, sums, sumsq);
    bn_prep_kernel<<<1, 128, 0, stream>>>(sums, sumsq, g2, be2, sc, sh);

    // ---- Layer 3
    gemm_bf16_kernel<128, true><<<gemmGrid, 256, 0, stream>>>(Yb, Wt3, dinv, sc, sh, U);
    gather128_kernel<<<gathGrid, 256, 0, stream>>>(csr, rowst, counts, U, dinv, b3, Yb);
    stats_kernel<<<512, 256, 0, stream>>>(Yb, sums, sumsq);
    bn_prep_kernel<<<1, 128, 0, stream>>>(sums, sumsq, g3, be3, sc, sh);

    // ---- Layer 4 (no BN stats; gather straight to d_out)
    gemm_bf16_kernel<64, true><<<gemmGrid, 256, 0, stream>>>(Yb, Wt4, dinv, sc, sh, U);
    gather64_kernel<<<gathGrid, 256, 0, stream>>>(csr, rowst, counts, U, dinv, b4, out);
}